// Round 6
// baseline (289.644 us; speedup 1.0000x reference)
//
#include <hip/hip_runtime.h>
#include <math.h>

// MERITS_T: dead-code-eliminated forward.
// B=1024 T=25 MED=145 LAB=1956 GLU=16 D=64 H=32 HID=1160
#define B_   1024
#define T_   25
#define MED_ 145
#define LAB_ 1956
#define GLU_ 16
#define D_   64
#define H_   32
#define HID_ 1160
#define KC_  978    // LAB_/2 per k-chunk
#define OUTN_ (B_ * MED_)   // 148480
#define W1N_ (D_ * HID_)    // 74240

// ---------------------------------------------------------------------------
// K_pre (fat kernel, 837 blocks x 512):
//   bid <  256: static_a — part[kc][row][d] partial GEMM lab @ sll_w1
//   bid <  836: w1c      — 580 blocks, 128 idx each, 4-way m-slice + LDS reduce
//   bid == 836: W3       — W3 = wo @ m2wv @ m2wo  (64x64)
__global__ __launch_bounds__(512) void k_pre(
    const float* __restrict__ lab, const float* __restrict__ sw1,
    const float* __restrict__ out_w1,
    const float* __restrict__ wo, const float* __restrict__ m2wv,
    const float* __restrict__ m2wo,
    float* __restrict__ part, float* __restrict__ w1c, float* __restrict__ W3) {
  __shared__ float smem[7824];  // 31.3 KB (aliased per phase)
  const int tid = threadIdx.x;
  const int bid = blockIdx.x;
  if (bid < 256) {
    const int b0 = (bid >> 1) * 8;
    const int kc = bid & 1;
    const int k0 = kc * KC_;
    float* lab_f = smem;          // [8][978]
    for (int e = tid; e < 8 * 489; e += 512) {
      int r = e / 489, i = e - r * 489;
      float2 v = ((const float2*)(lab + (size_t)(b0 + r) * LAB_ + k0))[i];
      lab_f[r * 978 + 2 * i] = v.x;
      lab_f[r * 978 + 2 * i + 1] = v.y;
    }
    __syncthreads();
    const int col = tid & 63;
    const int slice = tid >> 6;  // 0..7
    float acc[8] = {0.f, 0.f, 0.f, 0.f, 0.f, 0.f, 0.f, 0.f};
    #pragma unroll 2
    for (int k = slice; k < KC_; k += 8) {
      float w = sw1[(size_t)(k0 + k) * D_ + col];
      #pragma unroll
      for (int r = 0; r < 8; ++r) acc[r] = fmaf(lab_f[r * 978 + k], w, acc[r]);
    }
    __syncthreads();
    float* red = smem;            // [8][8][64] = 4096, aliases lab_f (done)
    #pragma unroll
    for (int r = 0; r < 8; ++r) red[(r * 8 + slice) * 64 + col] = acc[r];
    __syncthreads();
    {
      int r = tid >> 6, d = tid & 63;
      float v = 0.f;
      #pragma unroll
      for (int s2 = 0; s2 < 8; ++s2) v += red[(r * 8 + s2) * 64 + d];
      part[(size_t)kc * B_ * D_ + (size_t)(b0 + r) * D_ + d] = v;
    }
  } else if (bid < 836) {
    // w1c[idx] = sum_{m=0..144} out_w1[m*74240 + idx], idx block of 128
    const int b2 = bid - 256;          // 0..579
    const int i = tid & 127;
    const int msl = tid >> 7;          // 0..3
    const int idx = b2 * 128 + i;
    const int m0 = (msl * MED_) >> 2, m1 = ((msl + 1) * MED_) >> 2;
    const float* p = out_w1 + idx + (size_t)m0 * W1N_;
    float s = 0.f;
    #pragma unroll 4
    for (int m = m0; m < m1; ++m) {
      s += *p;
      p += (size_t)W1N_;
    }
    float* red = smem;  // [4][128]
    red[msl * 128 + i] = s;
    __syncthreads();
    if (tid < 128)
      w1c[b2 * 128 + tid] = red[tid] + red[128 + tid] + red[256 + tid] + red[384 + tid];
  } else {
    float* tmp = smem;  // 4096
    for (int e = tid; e < 4096; e += 512) {
      int i = e >> 6, j = e & 63;
      float s = 0.f;
      #pragma unroll 8
      for (int k = 0; k < 64; ++k) s = fmaf(wo[i * 64 + k], m2wv[k * 64 + j], s);
      tmp[e] = s;
    }
    __syncthreads();
    for (int e = tid; e < 4096; e += 512) {
      int i = e >> 6, j = e & 63;
      float s = 0.f;
      #pragma unroll 8
      for (int k = 0; k < 64; ++k) s = fmaf(tmp[i * 64 + k], m2wo[k * 64 + j], s);
      W3[e] = s;
    }
  }
}

// ---------------------------------------------------------------------------
// K_perb: per-batch fused (incl. static layer 2). One block (256 thr) per b.
__global__ __launch_bounds__(256) void k_perb(
    const float* __restrict__ glu, const float* __restrict__ tf,
    const float* __restrict__ med, const float* __restrict__ part,
    const float* __restrict__ sb1, const float* __restrict__ sw2,
    const float* __restrict__ sb2,
    const float* __restrict__ glu_w, const float* __restrict__ glu_b,
    const float* __restrict__ glu_gate, const float* __restrict__ med_w,
    const float* __restrict__ med_b, const float* __restrict__ med_gate,
    const float* __restrict__ wq, const float* __restrict__ wk,
    const float* __restrict__ wv, const float* __restrict__ W3,
    float* __restrict__ rr) {
  const int b = blockIdx.x;
  const int tid = threadIdx.x;
  const int d = tid & 63;
  const int s4 = tid >> 6;  // 0..3
  __shared__ float xin_s[T_][2 * GLU_];
  __shared__ float y_s[T_][H_];
  __shared__ float gate_s[T_];
  __shared__ float medrow_s[160];
  __shared__ float t1_s[D_];
  __shared__ float st_s[H_];
  __shared__ float pat_s[28][D_];   // rows 25..27 zero
  __shared__ float q0_s[D_];
  __shared__ float kh_s[T_][D_];
  __shared__ float vh_s[T_][D_];
  __shared__ float at_s[4][T_];
  __shared__ float o_s[D_];
  __shared__ float vec_s[D_];
  __shared__ float red4[4][D_];

  // P0: stage xin, med row 0; static t1 from part
  for (int e = tid; e < T_ * GLU_; e += 256) {
    int t = e >> 4, i = e & 15;
    xin_s[t][i] = glu[((size_t)b * T_ + t) * GLU_ + i];
    xin_s[t][GLU_ + i] = tf[((size_t)b * T_ + t) * GLU_ + i];
  }
  if (tid < MED_) medrow_s[tid] = med[(size_t)b * T_ * MED_ + tid];
  if (tid >= 192) {
    int dd = tid - 192;
    size_t o = (size_t)b * D_ + dd;
    t1_s[dd] = fmaxf(part[o] + part[(size_t)B_ * D_ + o] + sb1[dd], 0.f);
  }
  __syncthreads();

  // P1: y = tanh(xin @ glu_w + glu_b); st (last 32 threads)
  for (int e = tid; e < T_ * H_; e += 256) {
    int t = e >> 5, j = e & 31;
    float s = glu_b[j];
    #pragma unroll 8
    for (int i = 0; i < 2 * GLU_; ++i) s = fmaf(xin_s[t][i], glu_w[i * H_ + j], s);
    y_s[t][j] = tanhf(s);
  }
  if (tid >= 224) {
    int j = tid - 224;
    float s = sb2[j];
    #pragma unroll 8
    for (int dd = 0; dd < D_; ++dd) s = fmaf(t1_s[dd], sw2[dd * H_ + j], s);
    st_s[j] = fmaxf(s, 0.f);
  }
  __syncthreads();

  // P2: q0 partial gather (all) + gate (tid<200, 8-lane slices)
  {
    float x = 0.f;
    for (int m = s4; m < MED_; m += 4)
      if (medrow_s[m] > 0.9f) x += med_w[m * D_ + d];
    red4[s4][d] = x;
  }
  if (tid < 8 * T_) {
    int t = tid >> 3, sl = tid & 7;
    float s = 0.f;
    #pragma unroll
    for (int i = 0; i < 4; ++i) {
      int j = sl * 4 + i;
      s = fmaf(y_s[t][j], glu_gate[j], s);
    }
    s += __shfl_xor(s, 1);
    s += __shfl_xor(s, 2);
    s += __shfl_xor(s, 4);
    if (sl == 0) gate_s[t] = 1.f / (1.f + __expf(-s));
  }
  __syncthreads();

  // P3: q0 finalize (tid<64) + patient fill (all)
  if (tid < D_) {
    float x = med_b[tid] + red4[0][tid] + red4[1][tid] + red4[2][tid] + red4[3][tid];
    float v = x * med_gate[tid];
    #pragma unroll
    for (int off = 32; off > 0; off >>= 1) v += __shfl_xor(v, off);
    q0_s[tid] = x * (1.f / (1.f + __expf(-v)));
  }
  for (int e = tid; e < 28 * H_; e += 256) {
    int t = e >> 5, j = e & 31;
    if (t < T_) {
      pat_s[t][j] = y_s[t][j] * gate_s[t];
      pat_s[t][H_ + j] = st_s[j];
    } else {
      pat_s[t][j] = 0.f;
      pat_s[t][H_ + j] = 0.f;
    }
  }
  __syncthreads();

  // P4: kh, vh (thread (d,s4), 7 t's each) + qh partial
  {
    float aK[7] = {0.f, 0.f, 0.f, 0.f, 0.f, 0.f, 0.f};
    float aV[7] = {0.f, 0.f, 0.f, 0.f, 0.f, 0.f, 0.f};
    #pragma unroll 4
    for (int j = 0; j < D_; ++j) {
      float wkj = wk[j * D_ + d];
      float wvj = wv[j * D_ + d];
      #pragma unroll
      for (int i = 0; i < 7; ++i) {
        float p = pat_s[s4 + 4 * i][j];
        aK[i] = fmaf(p, wkj, aK[i]);
        aV[i] = fmaf(p, wvj, aV[i]);
      }
    }
    #pragma unroll
    for (int i = 0; i < 7; ++i) {
      int t = s4 + 4 * i;
      if (t < T_) { kh_s[t][d] = aK[i]; vh_s[t][d] = aV[i]; }
    }
  }
  {
    float qp = 0.f;
    #pragma unroll
    for (int i = 0; i < 16; ++i) {
      int j = s4 * 16 + i;
      qp = fmaf(q0_s[j], wq[j * D_ + d], qp);
    }
    red4[s4][d] = qp;
  }
  __syncthreads();

  // P5: qh reduce
  if (tid < D_) vec_s[tid] = red4[0][tid] + red4[1][tid] + red4[2][tid] + red4[3][tid];
  __syncthreads();

  // P6: scores + softmax, wave-parallel (tid<128; h = tid>>5, t = tid&31)
  if (tid < 128) {
    int h = tid >> 5, t = tid & 31;
    bool valid = t < T_;
    float sc = -3.4e38f;
    if (valid) {
      float a = 0.f;
      #pragma unroll
      for (int i = 0; i < 16; ++i) a = fmaf(vec_s[h * 16 + i], kh_s[t][h * 16 + i], a);
      sc = a * 0.25f;
    }
    float m = sc;
    #pragma unroll
    for (int off = 16; off > 0; off >>= 1) m = fmaxf(m, __shfl_xor(m, off, 32));
    float e = valid ? __expf(sc - m) : 0.f;
    float sum = e;
    #pragma unroll
    for (int off = 16; off > 0; off >>= 1) sum += __shfl_xor(sum, off, 32);
    if (valid) at_s[h][t] = e / sum;
  }
  __syncthreads();

  // P7: o = attn @ vh (tid<64)
  if (tid < D_) {
    int h = tid >> 4;
    float s = 0.f;
    #pragma unroll
    for (int t = 0; t < T_; ++t) s = fmaf(at_s[h][t], vh_s[t][tid], s);
    o_s[tid] = s;
  }
  __syncthreads();

  // P8: rr partial = o @ W3 (4-way)
  {
    float p = 0.f;
    #pragma unroll
    for (int i = 0; i < 16; ++i) {
      int j = s4 * 16 + i;
      p = fmaf(o_s[j], W3[j * D_ + d], p);
    }
    red4[s4][d] = p;
  }
  __syncthreads();

  // P9: rr = relu(...)
  if (tid < D_) {
    float v = red4[0][tid] + red4[1][tid] + red4[2][tid] + red4[3][tid];
    rr[(size_t)b * D_ + tid] = fmaxf(v, 0.f);
  }
}

// ---------------------------------------------------------------------------
// K_final: partial fused MLP. grid (64 rowtiles, 4 hid-quarters) x 640.
// Phase 1: hid quarter (16 x 290) = relu(rr@w1c+b1); thread (jj, row-octet).
// Phase 2: n-blocked 5x: thread (ngroup of 5 cols, row); hid read once per
//          (row,k) and reused across 5 cols -> p4[jq] (no atomics).
__global__ __launch_bounds__(640) void k_final(
    const float* __restrict__ rr, const float* __restrict__ w1c,
    const float* __restrict__ b1, const float* __restrict__ w2,
    float* __restrict__ p4) {
  const int tid = threadIdx.x;
  const int b0 = blockIdx.x * 16;
  const int jq = blockIdx.y;
  const int j0 = jq * 290;
  __shared__ float rr_s[16][D_];     // 4 KB
  __shared__ float hid_s[16][292];   // 18.7 KB
  for (int e = tid; e < 16 * D_; e += 640)
    ((float*)rr_s)[e] = rr[(size_t)b0 * D_ + e];
  __syncthreads();
  // phase 1
  if (tid < 580) {
    int jj = tid % 290, rh = tid / 290;  // rh: rows rh*8..rh*8+7
    const float* wp = w1c + (size_t)(j0 + jj);
    float bb = b1[j0 + jj];
    float acc[8] = {0.f, 0.f, 0.f, 0.f, 0.f, 0.f, 0.f, 0.f};
    #pragma unroll 4
    for (int d4 = 0; d4 < 16; ++d4) {
      float w0 = wp[(size_t)(4 * d4 + 0) * HID_];
      float w1v = wp[(size_t)(4 * d4 + 1) * HID_];
      float w2v = wp[(size_t)(4 * d4 + 2) * HID_];
      float w3v = wp[(size_t)(4 * d4 + 3) * HID_];
      #pragma unroll
      for (int r8 = 0; r8 < 8; ++r8) {
        float4 rv = *(const float4*)&rr_s[rh * 8 + r8][4 * d4];
        acc[r8] += rv.x * w0 + rv.y * w1v + rv.z * w2v + rv.w * w3v;
      }
    }
    #pragma unroll
    for (int r8 = 0; r8 < 8; ++r8)
      hid_s[rh * 8 + r8][jj] = fmaxf(acc[r8] + bb, 0.f);
  }
  __syncthreads();
  // phase 2: 464 threads; ng = 5-col group 0..28, r = row 0..15
  if (tid < 464) {
    int ng = tid >> 4;   // 0..28
    int r  = tid & 15;   // 0..15
    const float* w2p = w2 + (size_t)j0 * MED_ + ng * 5;
    float a0 = 0.f, a1 = 0.f, a2 = 0.f, a3 = 0.f, a4 = 0.f;
    #pragma unroll 2
    for (int k = 0; k < 290; ++k) {
      float h = hid_s[r][k];
      const float* wkp = w2p + (size_t)k * MED_;
      a0 = fmaf(h, wkp[0], a0);
      a1 = fmaf(h, wkp[1], a1);
      a2 = fmaf(h, wkp[2], a2);
      a3 = fmaf(h, wkp[3], a3);
      a4 = fmaf(h, wkp[4], a4);
    }
    float* dst = p4 + (size_t)jq * OUTN_ + (size_t)(b0 + r) * MED_ + ng * 5;
    dst[0] = a0; dst[1] = a1; dst[2] = a2; dst[3] = a3; dst[4] = a4;
  }
}

// ---------------------------------------------------------------------------
// K_combine: out = sum_jq p4[jq] + b2.  grid 580 x 256.
__global__ __launch_bounds__(256) void k_combine(
    const float* __restrict__ p4, const float* __restrict__ b2,
    float* __restrict__ out) {
  int idx = blockIdx.x * 256 + threadIdx.x;  // 148480 = 580*256
  int n = idx - (idx / MED_) * MED_;
  out[idx] = p4[idx] + p4[OUTN_ + idx] + p4[2 * OUTN_ + idx] +
             p4[3 * OUTN_ + idx] + b2[n];
}

// ---------------------------------------------------------------------------
extern "C" void kernel_launch(void* const* d_in, const int* in_sizes, int n_in,
                              void* d_out, int out_size, void* d_ws, size_t ws_size,
                              hipStream_t stream) {
  (void)in_sizes; (void)n_in; (void)out_size; (void)ws_size;
  const float* lab      = (const float*)d_in[0];
  const float* glu      = (const float*)d_in[1];
  const float* tf       = (const float*)d_in[2];
  const float* med      = (const float*)d_in[3];
  const float* sll_w1   = (const float*)d_in[7];
  const float* sll_b1   = (const float*)d_in[8];
  const float* sll_w2   = (const float*)d_in[9];
  const float* sll_b2   = (const float*)d_in[10];
  const float* glu_w    = (const float*)d_in[11];
  const float* glu_b    = (const float*)d_in[12];
  const float* glu_gate = (const float*)d_in[13];
  const float* med_w    = (const float*)d_in[14];
  const float* med_b    = (const float*)d_in[15];
  const float* med_gate = (const float*)d_in[16];
  const float* m1_wq    = (const float*)d_in[27];
  const float* m1_wk    = (const float*)d_in[28];
  const float* m1_wv    = (const float*)d_in[29];
  const float* m1_wo    = (const float*)d_in[30];
  const float* m2_wv    = (const float*)d_in[33];
  const float* m2_wo    = (const float*)d_in[34];
  const float* out_w1   = (const float*)d_in[35];
  const float* out_b1   = (const float*)d_in[36];
  const float* out_w2   = (const float*)d_in[37];
  const float* out_b2   = (const float*)d_in[38];
  float* out = (float*)d_out;

  float* ws   = (float*)d_ws;
  float* part = ws;                       // 2*1024*64 = 131072
  float* w1c  = part + 2 * B_ * D_;       // 64*1160   = 74240
  float* rr   = w1c + W1N_;               // 1024*64   = 65536
  float* W3   = rr + B_ * D_;             // 64*64     = 4096
  float* p4   = W3 + D_ * D_;             // 4*148480  = 593920

  hipLaunchKernelGGL(k_pre, dim3(837), dim3(512), 0, stream,
                     lab, sll_w1, out_w1, m1_wo, m2_wv, m2_wo, part, w1c, W3);
  hipLaunchKernelGGL(k_perb, dim3(B_), dim3(256), 0, stream,
                     glu, tf, med, part, sll_b1, sll_w2, sll_b2,
                     glu_w, glu_b, glu_gate, med_w, med_b, med_gate,
                     m1_wq, m1_wk, m1_wv, W3, rr);
  hipLaunchKernelGGL(k_final, dim3(B_ / 16, 4), dim3(640), 0, stream,
                     rr, w1c, out_b1, out_w2, p4);
  hipLaunchKernelGGL(k_combine, dim3(OUTN_ / 256), dim3(256), 0, stream,
                     p4, out_b2, out);
}

// Round 7
// 245.002 us; speedup vs baseline: 1.1822x; 1.1822x over previous
//
#include <hip/hip_runtime.h>
#include <math.h>

// MERITS_T: dead-code-eliminated forward.
// B=1024 T=25 MED=145 LAB=1956 GLU=16 D=64 H=32 HID=1160
#define B_   1024
#define T_   25
#define MED_ 145
#define LAB_ 1956
#define GLU_ 16
#define D_   64
#define H_   32
#define HID_ 1160
#define KC_  978    // LAB_/2 per k-chunk
#define OUTN_ (B_ * MED_)   // 148480
#define W1N_ (D_ * HID_)    // 74240

// ---------------------------------------------------------------------------
// K_pre (fat kernel, 837 blocks x 512):
//   bid <  256: static_a — part[kc][row][d] partial GEMM lab @ sll_w1
//   bid <  836: w1c      — 580 blocks, 128 idx each, 4-way m-slice + LDS reduce
//   bid == 836: W3       — W3 = wo @ m2wv @ m2wo  (64x64)
__global__ __launch_bounds__(512) void k_pre(
    const float* __restrict__ lab, const float* __restrict__ sw1,
    const float* __restrict__ out_w1,
    const float* __restrict__ wo, const float* __restrict__ m2wv,
    const float* __restrict__ m2wo,
    float* __restrict__ part, float* __restrict__ w1c, float* __restrict__ W3) {
  __shared__ float smem[7824];  // 31.3 KB (aliased per phase)
  const int tid = threadIdx.x;
  const int bid = blockIdx.x;
  if (bid < 256) {
    const int b0 = (bid >> 1) * 8;
    const int kc = bid & 1;
    const int k0 = kc * KC_;
    float* lab_f = smem;          // [8][978]
    for (int e = tid; e < 8 * 489; e += 512) {
      int r = e / 489, i = e - r * 489;
      float2 v = ((const float2*)(lab + (size_t)(b0 + r) * LAB_ + k0))[i];
      lab_f[r * 978 + 2 * i] = v.x;
      lab_f[r * 978 + 2 * i + 1] = v.y;
    }
    __syncthreads();
    const int col = tid & 63;
    const int slice = tid >> 6;  // 0..7
    float acc[8] = {0.f, 0.f, 0.f, 0.f, 0.f, 0.f, 0.f, 0.f};
    #pragma unroll 2
    for (int k = slice; k < KC_; k += 8) {
      float w = sw1[(size_t)(k0 + k) * D_ + col];
      #pragma unroll
      for (int r = 0; r < 8; ++r) acc[r] = fmaf(lab_f[r * 978 + k], w, acc[r]);
    }
    __syncthreads();
    float* red = smem;            // [8][8][64] = 4096, aliases lab_f (done)
    #pragma unroll
    for (int r = 0; r < 8; ++r) red[(r * 8 + slice) * 64 + col] = acc[r];
    __syncthreads();
    {
      int r = tid >> 6, d = tid & 63;
      float v = 0.f;
      #pragma unroll
      for (int s2 = 0; s2 < 8; ++s2) v += red[(r * 8 + s2) * 64 + d];
      part[(size_t)kc * B_ * D_ + (size_t)(b0 + r) * D_ + d] = v;
    }
  } else if (bid < 836) {
    // w1c[idx] = sum_{m=0..144} out_w1[m*74240 + idx], idx block of 128
    const int b2 = bid - 256;          // 0..579
    const int i = tid & 127;
    const int msl = tid >> 7;          // 0..3
    const int idx = b2 * 128 + i;
    const int m0 = (msl * MED_) >> 2, m1 = ((msl + 1) * MED_) >> 2;
    const float* p = out_w1 + idx + (size_t)m0 * W1N_;
    float s = 0.f;
    #pragma unroll 4
    for (int m = m0; m < m1; ++m) {
      s += *p;
      p += (size_t)W1N_;
    }
    float* red = smem;  // [4][128]
    red[msl * 128 + i] = s;
    __syncthreads();
    if (tid < 128)
      w1c[b2 * 128 + tid] = red[tid] + red[128 + tid] + red[256 + tid] + red[384 + tid];
  } else {
    float* tmp = smem;  // 4096
    for (int e = tid; e < 4096; e += 512) {
      int i = e >> 6, j = e & 63;
      float s = 0.f;
      #pragma unroll 8
      for (int k = 0; k < 64; ++k) s = fmaf(wo[i * 64 + k], m2wv[k * 64 + j], s);
      tmp[e] = s;
    }
    __syncthreads();
    for (int e = tid; e < 4096; e += 512) {
      int i = e >> 6, j = e & 63;
      float s = 0.f;
      #pragma unroll 8
      for (int k = 0; k < 64; ++k) s = fmaf(tmp[i * 64 + k], m2wo[k * 64 + j], s);
      W3[e] = s;
    }
  }
}

// ---------------------------------------------------------------------------
// K_perb: per-batch fused (incl. static layer 2). One block (256 thr) per b.
__global__ __launch_bounds__(256) void k_perb(
    const float* __restrict__ glu, const float* __restrict__ tf,
    const float* __restrict__ med, const float* __restrict__ part,
    const float* __restrict__ sb1, const float* __restrict__ sw2,
    const float* __restrict__ sb2,
    const float* __restrict__ glu_w, const float* __restrict__ glu_b,
    const float* __restrict__ glu_gate, const float* __restrict__ med_w,
    const float* __restrict__ med_b, const float* __restrict__ med_gate,
    const float* __restrict__ wq, const float* __restrict__ wk,
    const float* __restrict__ wv, const float* __restrict__ W3,
    float* __restrict__ rr) {
  const int b = blockIdx.x;
  const int tid = threadIdx.x;
  const int d = tid & 63;
  const int s4 = tid >> 6;  // 0..3
  __shared__ float xin_s[T_][2 * GLU_];
  __shared__ float y_s[T_][H_];
  __shared__ float gate_s[T_];
  __shared__ float medrow_s[160];
  __shared__ float t1_s[D_];
  __shared__ float st_s[H_];
  __shared__ float pat_s[28][D_];   // rows 25..27 zero
  __shared__ float q0_s[D_];
  __shared__ float kh_s[T_][D_];
  __shared__ float vh_s[T_][D_];
  __shared__ float at_s[4][T_];
  __shared__ float o_s[D_];
  __shared__ float vec_s[D_];
  __shared__ float red4[4][D_];

  // P0: stage xin, med row 0; static t1 from part
  for (int e = tid; e < T_ * GLU_; e += 256) {
    int t = e >> 4, i = e & 15;
    xin_s[t][i] = glu[((size_t)b * T_ + t) * GLU_ + i];
    xin_s[t][GLU_ + i] = tf[((size_t)b * T_ + t) * GLU_ + i];
  }
  if (tid < MED_) medrow_s[tid] = med[(size_t)b * T_ * MED_ + tid];
  if (tid >= 192) {
    int dd = tid - 192;
    size_t o = (size_t)b * D_ + dd;
    t1_s[dd] = fmaxf(part[o] + part[(size_t)B_ * D_ + o] + sb1[dd], 0.f);
  }
  __syncthreads();

  // P1: y = tanh(xin @ glu_w + glu_b); st (last 32 threads)
  for (int e = tid; e < T_ * H_; e += 256) {
    int t = e >> 5, j = e & 31;
    float s = glu_b[j];
    #pragma unroll 8
    for (int i = 0; i < 2 * GLU_; ++i) s = fmaf(xin_s[t][i], glu_w[i * H_ + j], s);
    y_s[t][j] = tanhf(s);
  }
  if (tid >= 224) {
    int j = tid - 224;
    float s = sb2[j];
    #pragma unroll 8
    for (int dd = 0; dd < D_; ++dd) s = fmaf(t1_s[dd], sw2[dd * H_ + j], s);
    st_s[j] = fmaxf(s, 0.f);
  }
  __syncthreads();

  // P2: q0 partial gather (all) + gate (tid<200, 8-lane slices)
  {
    float x = 0.f;
    for (int m = s4; m < MED_; m += 4)
      if (medrow_s[m] > 0.9f) x += med_w[m * D_ + d];
    red4[s4][d] = x;
  }
  if (tid < 8 * T_) {
    int t = tid >> 3, sl = tid & 7;
    float s = 0.f;
    #pragma unroll
    for (int i = 0; i < 4; ++i) {
      int j = sl * 4 + i;
      s = fmaf(y_s[t][j], glu_gate[j], s);
    }
    s += __shfl_xor(s, 1);
    s += __shfl_xor(s, 2);
    s += __shfl_xor(s, 4);
    if (sl == 0) gate_s[t] = 1.f / (1.f + __expf(-s));
  }
  __syncthreads();

  // P3: q0 finalize (tid<64) + patient fill (all)
  if (tid < D_) {
    float x = med_b[tid] + red4[0][tid] + red4[1][tid] + red4[2][tid] + red4[3][tid];
    float v = x * med_gate[tid];
    #pragma unroll
    for (int off = 32; off > 0; off >>= 1) v += __shfl_xor(v, off);
    q0_s[tid] = x * (1.f / (1.f + __expf(-v)));
  }
  for (int e = tid; e < 28 * H_; e += 256) {
    int t = e >> 5, j = e & 31;
    if (t < T_) {
      pat_s[t][j] = y_s[t][j] * gate_s[t];
      pat_s[t][H_ + j] = st_s[j];
    } else {
      pat_s[t][j] = 0.f;
      pat_s[t][H_ + j] = 0.f;
    }
  }
  __syncthreads();

  // P4: kh, vh (thread (d,s4), 7 t's each) + qh partial
  {
    float aK[7] = {0.f, 0.f, 0.f, 0.f, 0.f, 0.f, 0.f};
    float aV[7] = {0.f, 0.f, 0.f, 0.f, 0.f, 0.f, 0.f};
    #pragma unroll 4
    for (int j = 0; j < D_; ++j) {
      float wkj = wk[j * D_ + d];
      float wvj = wv[j * D_ + d];
      #pragma unroll
      for (int i = 0; i < 7; ++i) {
        float p = pat_s[s4 + 4 * i][j];
        aK[i] = fmaf(p, wkj, aK[i]);
        aV[i] = fmaf(p, wvj, aV[i]);
      }
    }
    #pragma unroll
    for (int i = 0; i < 7; ++i) {
      int t = s4 + 4 * i;
      if (t < T_) { kh_s[t][d] = aK[i]; vh_s[t][d] = aV[i]; }
    }
  }
  {
    float qp = 0.f;
    #pragma unroll
    for (int i = 0; i < 16; ++i) {
      int j = s4 * 16 + i;
      qp = fmaf(q0_s[j], wq[j * D_ + d], qp);
    }
    red4[s4][d] = qp;
  }
  __syncthreads();

  // P5: qh reduce
  if (tid < D_) vec_s[tid] = red4[0][tid] + red4[1][tid] + red4[2][tid] + red4[3][tid];
  __syncthreads();

  // P6: scores + softmax, wave-parallel (tid<128; h = tid>>5, t = tid&31)
  if (tid < 128) {
    int h = tid >> 5, t = tid & 31;
    bool valid = t < T_;
    float sc = -3.4e38f;
    if (valid) {
      float a = 0.f;
      #pragma unroll
      for (int i = 0; i < 16; ++i) a = fmaf(vec_s[h * 16 + i], kh_s[t][h * 16 + i], a);
      sc = a * 0.25f;
    }
    float m = sc;
    #pragma unroll
    for (int off = 16; off > 0; off >>= 1) m = fmaxf(m, __shfl_xor(m, off, 32));
    float e = valid ? __expf(sc - m) : 0.f;
    float sum = e;
    #pragma unroll
    for (int off = 16; off > 0; off >>= 1) sum += __shfl_xor(sum, off, 32);
    if (valid) at_s[h][t] = e / sum;
  }
  __syncthreads();

  // P7: o = attn @ vh (tid<64)
  if (tid < D_) {
    int h = tid >> 4;
    float s = 0.f;
    #pragma unroll
    for (int t = 0; t < T_; ++t) s = fmaf(at_s[h][t], vh_s[t][tid], s);
    o_s[tid] = s;
  }
  __syncthreads();

  // P8: rr partial = o @ W3 (4-way)
  {
    float p = 0.f;
    #pragma unroll
    for (int i = 0; i < 16; ++i) {
      int j = s4 * 16 + i;
      p = fmaf(o_s[j], W3[j * D_ + d], p);
    }
    red4[s4][d] = p;
  }
  __syncthreads();

  // P9: rr = relu(...)
  if (tid < D_) {
    float v = red4[0][tid] + red4[1][tid] + red4[2][tid] + red4[3][tid];
    rr[(size_t)b * D_ + tid] = fmaxf(v, 0.f);
  }
}

// ---------------------------------------------------------------------------
// K_final: partial fused MLP. grid (64 rowtiles, 4 hid-quarters) x 640.
// Phase 1: hid quarter (16 x 290) = relu(rr@w1c+b1); thread (jj, row-octet).
// Phase 2: w2 LDS-staged in 10 chunks of 29 rows (reg-prefetched one chunk
//          ahead); thread (rg row-quad, n): 1 conflict-free w2t read +
//          4 hid broadcasts + 4 FMA per k. -> p4[jq] (no atomics).
__global__ __launch_bounds__(640) void k_final(
    const float* __restrict__ rr, const float* __restrict__ w1c,
    const float* __restrict__ b1, const float* __restrict__ w2,
    float* __restrict__ p4) {
  const int tid = threadIdx.x;
  const int b0 = blockIdx.x * 16;
  const int jq = blockIdx.y;
  const int j0 = jq * 290;
  __shared__ float rr_s[16][D_];     // 4 KB
  __shared__ float hid_s[16][292];   // 18.7 KB
  __shared__ float w2t[29 * MED_];   // 16.8 KB (4205 floats)
  for (int e = tid; e < 16 * D_; e += 640)
    ((float*)rr_s)[e] = rr[(size_t)b0 * D_ + e];
  // prefetch w2 chunk 0 into registers (latency hides under phase 1)
  float pre[7];
  {
    const float* src = w2 + (size_t)j0 * MED_;
    #pragma unroll
    for (int i = 0; i < 7; ++i) {
      int e = tid + i * 640;
      pre[i] = (e < 29 * MED_) ? src[e] : 0.f;
    }
  }
  __syncthreads();
  // phase 1
  if (tid < 580) {
    int jj = tid % 290, rh = tid / 290;  // rh: rows rh*8..rh*8+7
    const float* wp = w1c + (size_t)(j0 + jj);
    float bb = b1[j0 + jj];
    float acc[8] = {0.f, 0.f, 0.f, 0.f, 0.f, 0.f, 0.f, 0.f};
    #pragma unroll 4
    for (int d4 = 0; d4 < 16; ++d4) {
      float w0 = wp[(size_t)(4 * d4 + 0) * HID_];
      float w1v = wp[(size_t)(4 * d4 + 1) * HID_];
      float w2v = wp[(size_t)(4 * d4 + 2) * HID_];
      float w3v = wp[(size_t)(4 * d4 + 3) * HID_];
      #pragma unroll
      for (int r8 = 0; r8 < 8; ++r8) {
        float4 rv = *(const float4*)&rr_s[rh * 8 + r8][4 * d4];
        acc[r8] += rv.x * w0 + rv.y * w1v + rv.z * w2v + rv.w * w3v;
      }
    }
    #pragma unroll
    for (int r8 = 0; r8 < 8; ++r8)
      hid_s[rh * 8 + r8][jj] = fmaxf(acc[r8] + bb, 0.f);
  }
  // phase 2: thread (rg = row-quad 0..3, n = col 0..144); 580 active
  const int n = tid % MED_, rg = tid / MED_;
  float a0 = 0.f, a1 = 0.f, a2 = 0.f, a3 = 0.f;
  for (int c = 0; c < 10; ++c) {
    __syncthreads();  // c==0: phase-1 hid ready; c>0: prev compute done
    #pragma unroll
    for (int i = 0; i < 7; ++i) {
      int e = tid + i * 640;
      if (e < 29 * MED_) w2t[e] = pre[i];
    }
    __syncthreads();
    if (c < 9) {  // issue next-chunk loads; overlap with compute below
      const float* src = w2 + (size_t)(j0 + (c + 1) * 29) * MED_;
      #pragma unroll
      for (int i = 0; i < 7; ++i) {
        int e = tid + i * 640;
        pre[i] = (e < 29 * MED_) ? src[e] : 0.f;
      }
    }
    if (tid < 580) {
      const float* hp0 = &hid_s[rg * 4 + 0][c * 29];
      const float* hp1 = &hid_s[rg * 4 + 1][c * 29];
      const float* hp2 = &hid_s[rg * 4 + 2][c * 29];
      const float* hp3 = &hid_s[rg * 4 + 3][c * 29];
      const float* wt = w2t + n;
      #pragma unroll
      for (int k = 0; k < 29; ++k) {
        float wv = wt[k * MED_];
        a0 = fmaf(hp0[k], wv, a0);
        a1 = fmaf(hp1[k], wv, a1);
        a2 = fmaf(hp2[k], wv, a2);
        a3 = fmaf(hp3[k], wv, a3);
      }
    }
  }
  if (tid < 580) {
    float* dst = p4 + (size_t)jq * OUTN_ + (size_t)(b0 + rg * 4) * MED_ + n;
    dst[0 * MED_] = a0;
    dst[1 * MED_] = a1;
    dst[2 * MED_] = a2;
    dst[3 * MED_] = a3;
  }
}

// ---------------------------------------------------------------------------
// K_combine: out = sum_jq p4[jq] + b2.  grid 580 x 256.
__global__ __launch_bounds__(256) void k_combine(
    const float* __restrict__ p4, const float* __restrict__ b2,
    float* __restrict__ out) {
  int idx = blockIdx.x * 256 + threadIdx.x;  // 148480 = 580*256
  int n = idx - (idx / MED_) * MED_;
  out[idx] = p4[idx] + p4[OUTN_ + idx] + p4[2 * OUTN_ + idx] +
             p4[3 * OUTN_ + idx] + b2[n];
}

// ---------------------------------------------------------------------------
extern "C" void kernel_launch(void* const* d_in, const int* in_sizes, int n_in,
                              void* d_out, int out_size, void* d_ws, size_t ws_size,
                              hipStream_t stream) {
  (void)in_sizes; (void)n_in; (void)out_size; (void)ws_size;
  const float* lab      = (const float*)d_in[0];
  const float* glu      = (const float*)d_in[1];
  const float* tf       = (const float*)d_in[2];
  const float* med      = (const float*)d_in[3];
  const float* sll_w1   = (const float*)d_in[7];
  const float* sll_b1   = (const float*)d_in[8];
  const float* sll_w2   = (const float*)d_in[9];
  const float* sll_b2   = (const float*)d_in[10];
  const float* glu_w    = (const float*)d_in[11];
  const float* glu_b    = (const float*)d_in[12];
  const float* glu_gate = (const float*)d_in[13];
  const float* med_w    = (const float*)d_in[14];
  const float* med_b    = (const float*)d_in[15];
  const float* med_gate = (const float*)d_in[16];
  const float* m1_wq    = (const float*)d_in[27];
  const float* m1_wk    = (const float*)d_in[28];
  const float* m1_wv    = (const float*)d_in[29];
  const float* m1_wo    = (const float*)d_in[30];
  const float* m2_wv    = (const float*)d_in[33];
  const float* m2_wo    = (const float*)d_in[34];
  const float* out_w1   = (const float*)d_in[35];
  const float* out_b1   = (const float*)d_in[36];
  const float* out_w2   = (const float*)d_in[37];
  const float* out_b2   = (const float*)d_in[38];
  float* out = (float*)d_out;

  float* ws   = (float*)d_ws;
  float* part = ws;                       // 2*1024*64 = 131072
  float* w1c  = part + 2 * B_ * D_;       // 64*1160   = 74240
  float* rr   = w1c + W1N_;               // 1024*64   = 65536
  float* W3   = rr + B_ * D_;             // 64*64     = 4096
  float* p4   = W3 + D_ * D_;             // 4*148480  = 593920

  hipLaunchKernelGGL(k_pre, dim3(837), dim3(512), 0, stream,
                     lab, sll_w1, out_w1, m1_wo, m2_wv, m2_wo, part, w1c, W3);
  hipLaunchKernelGGL(k_perb, dim3(B_), dim3(256), 0, stream,
                     glu, tf, med, part, sll_b1, sll_w2, sll_b2,
                     glu_w, glu_b, glu_gate, med_w, med_b, med_gate,
                     m1_wq, m1_wk, m1_wv, W3, rr);
  hipLaunchKernelGGL(k_final, dim3(B_ / 16, 4), dim3(640), 0, stream,
                     rr, w1c, out_b1, out_w2, p4);
  hipLaunchKernelGGL(k_combine, dim3(OUTN_ / 256), dim3(256), 0, stream,
                     p4, out_b2, out);
}